// Round 7
// baseline (752.974 us; speedup 1.0000x reference)
//
#include <hip/hip_runtime.h>

#define Tv 128

typedef float v2 __attribute__((ext_vector_type(2)));

__device__ __forceinline__ v2 pkfma(v2 a, v2 b, v2 c) {
  return __builtin_elementwise_fma(a, b, c);
}

// ---- DPP / cross-lane helpers
template<int CTRL>
__device__ __forceinline__ float dppx(float x) {
  return __int_as_float(__builtin_amdgcn_update_dpp(0, __float_as_int(x), CTRL, 0xF, 0xF, true));
}
__device__ __forceinline__ float dpp_rm(float x, int ctrl, int rm) {
  switch (ctrl) {
    default: return 0.f;
    case 0x111: return __int_as_float(__builtin_amdgcn_update_dpp(0, __float_as_int(x), 0x111, 0xF, 0xF, true));
    case 0x112: return __int_as_float(__builtin_amdgcn_update_dpp(0, __float_as_int(x), 0x112, 0xF, 0xF, true));
    case 0x114: return __int_as_float(__builtin_amdgcn_update_dpp(0, __float_as_int(x), 0x114, 0xF, 0xF, true));
    case 0x118: return __int_as_float(__builtin_amdgcn_update_dpp(0, __float_as_int(x), 0x118, 0xF, 0xF, true));
    case 0x142: return __int_as_float(__builtin_amdgcn_update_dpp(0, __float_as_int(x), 0x142, 0xA, 0xF, true));
    case 0x143: return __int_as_float(__builtin_amdgcn_update_dpp(0, __float_as_int(x), 0x143, 0xC, 0xF, true));
  }
}
// full-wave64 sum, broadcast via readlane(63)
__device__ __forceinline__ float wave_sum(float x) {
  x += dpp_rm(x, 0x111, 0xF);
  x += dpp_rm(x, 0x112, 0xF);
  x += dpp_rm(x, 0x114, 0xF);
  x += dpp_rm(x, 0x118, 0xF);
  x += dpp_rm(x, 0x142, 0xA);
  x += dpp_rm(x, 0x143, 0xC);
  return __int_as_float(__builtin_amdgcn_readlane(__float_as_int(x), 63));
}
template<int M>
__device__ __forceinline__ float lane_xor(float x) {
  if constexpr (M == 1)       return dppx<0xB1>(x);    // quad_perm [1,0,3,2]
  else if constexpr (M == 2)  return dppx<0x4E>(x);    // quad_perm [2,3,0,1]
  else if constexpr (M == 8)  return dppx<0x128>(x);   // row_ror:8 == xor8
  else if constexpr (M == 32) return __shfl_xor(x, 32, 64);
  else return __int_as_float(__builtin_amdgcn_ds_swizzle(__float_as_int(x), (M << 10) | 0x1F));
}
__device__ __forceinline__ float bperm(int addr, float x) {
  return __int_as_float(__builtin_amdgcn_ds_bpermute(addr, __float_as_int(x)));
}
__device__ __forceinline__ float rdlane(float x, int l) {
  return __int_as_float(__builtin_amdgcn_readlane(__float_as_int(x), l));
}
__device__ __forceinline__ float fast_rcp(float x){ return __builtin_amdgcn_rcpf(x); }
__device__ __forceinline__ float fast_rsq(float x){ return __builtin_amdgcn_rsqf(x); }
__device__ __forceinline__ float tanh_(float x){
  float e = __expf(2.0f * x);
  return 1.0f - 2.0f * fast_rcp(e + 1.0f);
}
__device__ __forceinline__ float sigm_(float x){
  return fast_rcp(1.0f + __expf(-x));
}

// State: 256 amps = 8 regs x 32 lanes, packed as v2 S[4]; s[r] = S[r>>1][r&1].
// idx = reg(3b: bits 7..5) | l5(5b: bits 4..0).
// q0 -> reg bit2 (S[k]<->S[k+2]); q1 -> reg bit1 (S[k]<->S[k+1]); q2 -> reg bit0 (x<->y);
// q3..q7 -> lane masks 16,8,4,2,1.  (q3,q5 handled in fused CNOT+RY burst)
template<int Q>
__device__ __forceinline__ void ry_pk(v2* S, float cc, float ss, int l5) {
  const v2 cc2 = {cc, cc};
  if constexpr (Q == 0) {
    const v2 ss2 = {ss, ss};
    #pragma unroll
    for (int k = 0; k < 2; k++) {
      v2 a0 = S[k], a1 = S[k + 2];
      S[k]     = pkfma(cc2, a0, -(ss2 * a1));
      S[k + 2] = pkfma(ss2, a0,  (cc2 * a1));
    }
  } else if constexpr (Q == 1) {
    const v2 ss2 = {ss, ss};
    #pragma unroll
    for (int k = 0; k < 4; k += 2) {
      v2 a0 = S[k], a1 = S[k + 1];
      S[k]     = pkfma(cc2, a0, -(ss2 * a1));
      S[k + 1] = pkfma(ss2, a0,  (cc2 * a1));
    }
  } else if constexpr (Q == 2) {
    const v2 nss = {-ss, ss};
    #pragma unroll
    for (int k = 0; k < 4; k++) {
      v2 a = S[k];
      v2 sw = __builtin_shufflevector(a, a, 1, 0);
      S[k] = pkfma(cc2, a, nss * sw);
    }
  } else {
    constexpr int m = 16 >> (Q - 3);
    float ssn = (l5 & m) ? ss : -ss;
    const v2 ssn2 = {ssn, ssn};
    #pragma unroll
    for (int k = 0; k < 4; k++) {
      v2 o;
      o.x = lane_xor<m>(S[k].x);
      o.y = lane_xor<m>(S[k].y);
      S[k] = pkfma(cc2, S[k], ssn2 * o);
    }
  }
}

struct __align__(16) SMem {
  float cs[4][66];     // per gate: (cos,sin) at [(l*8+q)*2]
  float ipb[8][4];     // (ip_b, in_g, in_b, 0)
  float zbuf[32];      // z[gate][qubit]
  float embp[2][2];    // emb-LN partials (s1,s2)
  float projp2[8][8];  // proj 16-group partials [o8][w*4+g]
  float outp[2][4];    // out-epilogue partials (init: SW/KB)
};

__global__ __launch_bounds__(128, 2) void qlstm_kernel(
    const float* __restrict__ x,     const float* __restrict__ pe,
    const float* __restrict__ emb_w, const float* __restrict__ emb_b,
    const float* __restrict__ emb_g, const float* __restrict__ emb_bt,
    const float* __restrict__ ip_w,  const float* __restrict__ ip_b,
    const float* __restrict__ in_g,  const float* __restrict__ in_b,
    const float* __restrict__ wq_i,  const float* __restrict__ wq_f,
    const float* __restrict__ wq_gt, const float* __restrict__ wq_o,
    const float* __restrict__ pi_w,  const float* __restrict__ pi_b,
    const float* __restrict__ pf_w,  const float* __restrict__ pf_b,
    const float* __restrict__ pg_w,  const float* __restrict__ pg_b,
    const float* __restrict__ po_w,  const float* __restrict__ po_b,
    const float* __restrict__ on_g,  const float* __restrict__ on_b,
    const float* __restrict__ out_w, const float* __restrict__ out_b,
    float* __restrict__ out)
{
  __shared__ SMem sm;
  const int tid = threadIdx.x;          // 0..127 = row j
  const int b   = blockIdx.x;
  const int w   = tid >> 6;             // wave 0/1
  const int L   = tid & 63;
  const int l5  = L & 31;
  const int gate = w * 2 + (L >> 5);    // 0..3 = i,f,g,o
  const int o8  = L & 7;

  // ---- stage (cos,sin) table
  {
    int gg = tid >> 5, rem = tid & 31;
    const float* wsel = (gg == 0) ? wq_i : (gg == 1) ? wq_f : (gg == 2) ? wq_gt : wq_o;
    float th = wsel[rem] * 0.5f;
    sm.cs[gg][rem * 2]     = __cosf(th);
    sm.cs[gg][rem * 2 + 1] = __sinf(th);
  }
  if (tid < 8) {
    sm.ipb[tid][0] = ip_b[tid];
    sm.ipb[tid][1] = in_g[tid];
    sm.ipb[tid][2] = in_b[tid];
    sm.ipb[tid][3] = 0.0f;
  }

  // ---- persistent per-thread weights (row j = tid)
  const int j = tid;
  v2 EW[4];
  {
    float4 a = *reinterpret_cast<const float4*>(emb_w + j * 8);
    float4 c = *reinterpret_cast<const float4*>(emb_w + j * 8 + 4);
    EW[0] = {a.x, a.y}; EW[1] = {a.z, a.w}; EW[2] = {c.x, c.y}; EW[3] = {c.z, c.w};
  }
  float ebb = emb_b[j], egg = emb_g[j], ebt = emb_bt[j];
  v2 IPW1[4], IPW2[4];
  #pragma unroll
  for (int k = 0; k < 4; k++) {
    IPW1[k] = {ip_w[(2 * k) * 256 + j],       ip_w[(2 * k + 1) * 256 + j]};
    IPW2[k] = {ip_w[(2 * k) * 256 + 128 + j], ip_w[(2 * k + 1) * 256 + 128 + j]};
  }
  v2 GW[4][4];
  #pragma unroll
  for (int gg = 0; gg < 4; gg++) {
    const float* pw = (gg == 0) ? pi_w : (gg == 1) ? pf_w : (gg == 2) ? pg_w : po_w;
    float4 a = *reinterpret_cast<const float4*>(pw + j * 8);
    float4 c = *reinterpret_cast<const float4*>(pw + j * 8 + 4);
    GW[gg][0] = {a.x, a.y}; GW[gg][1] = {a.z, a.w};
    GW[gg][2] = {c.x, c.y}; GW[gg][3] = {c.z, c.w};
  }
  float gb[4] = {pi_b[j], pf_b[j], pg_b[j], po_b[j]};
  float ong = on_g[j], onb = on_b[j], ow_ = out_w[j];
  float outb = out_b[0];
  float a_ = ong * ow_;

  // Composed CNOT permutation P (linear over GF(2)); partner addresses for q3/q5
  // fused RYs pull straight through P: P(l^16)=P(l)^28, P(l^4)=P(l)^7, P(l^20)=P(l)^27.
  int aP0[4], aP1[4];
  {
    const int grp = L & 32;
    int l1 = l5 ^ ((l5 & 16) >> 1) ^ ((l5 & 4) >> 1);
    int lb = l1 ^ ((l1 & 8) >> 1) ^ ((l1 & 2) >> 1);
    int a0 = (grp | lb) << 2;
    int a1 = a0 ^ 64;         // parity-1 base (lb^16)
    aP0[0] = a0; aP0[1] = a0 ^ 112; aP0[2] = a0 ^ 28; aP0[3] = a0 ^ 108;
    aP1[0] = a1; aP1[1] = a1 ^ 112; aP1[2] = a1 ^ 28; aP1[3] = a1 ^ 108;
  }

  const float* csg = sm.cs[gate];
  float h = 0.f, c = 0.f;
  const float* xbase = x + (size_t)b * Tv * 8;

  // ---- pre-loop: e_0 + SW/KB partials, single barrier
  float e;
  {
    float4 a = *reinterpret_cast<const float4*>(xbase);
    float4 cq = *reinterpret_cast<const float4*>(xbase + 4);
    v2 XT[4] = {{a.x,a.y},{a.z,a.w},{cq.x,cq.y},{cq.z,cq.w}};
    v2 acc = XT[0] * EW[0];
    acc = pkfma(XT[1], EW[1], acc);
    acc = pkfma(XT[2], EW[2], acc);
    acc = pkfma(XT[3], EW[3], acc);
    float er = ebb + acc.x + acc.y;
    float s1 = wave_sum(er), s2 = wave_sum(er * er);
    float r0 = wave_sum(a_), r1 = wave_sum(onb * ow_);
    if (L == 0) {
      sm.embp[w][0] = s1; sm.embp[w][1] = s2;
      sm.outp[w][0] = r0; sm.outp[w][1] = r1;
    }
    __syncthreads();
    s1 = sm.embp[0][0] + sm.embp[1][0];
    s2 = sm.embp[0][1] + sm.embp[1][1];
    float mn = s1 * 0.0078125f;
    float vr = fmaf(s2, 0.0078125f, -mn * mn);
    float inv = fast_rsq(vr + 1e-5f);
    e = (er - mn) * inv * egg + ebt + pe[j];
  }
  const float SW = sm.outp[0][0] + sm.outp[1][0];
  const float KB = sm.outp[0][1] + sm.outp[1][1] + outb;

  #pragma unroll 1
  for (int t = 0; t < Tv; t++) {
    // ---- prefetch next x,pe
    v2 XN[4]; float pen;
    {
      int tn = (t + 1) & (Tv - 1);
      float4 a = *reinterpret_cast<const float4*>(xbase + tn * 8);
      float4 cq = *reinterpret_cast<const float4*>(xbase + tn * 8 + 4);
      XN[0] = {a.x,a.y}; XN[1] = {a.z,a.w}; XN[2] = {cq.x,cq.y}; XN[3] = {cq.z,cq.w};
      pen = pe[tn * 128 + j];
    }

    // ---- proj: p_o = e*ipw1[o] + h*ipw2[o] (packed), butterfly to 16-group partials
    const v2 e2 = {e, e}, h2 = {h, h};
    v2 P2[4];
    #pragma unroll
    for (int k = 0; k < 4; k++)
      P2[k] = pkfma(e2, IPW1[k], h2 * IPW2[k]);
    const int bb0 = L & 1, bb1 = L & 2, bb2 = L & 4;
    float q_[4];
    #pragma unroll
    for (int k = 0; k < 4; k++) {
      float keep = bb0 ? P2[k].y : P2[k].x;
      float send = bb0 ? P2[k].x : P2[k].y;
      q_[k] = keep + lane_xor<1>(send);
    }
    float r_[2];
    #pragma unroll
    for (int k = 0; k < 2; k++) {
      float keep = bb1 ? q_[2 * k + 1] : q_[2 * k];
      float send = bb1 ? q_[2 * k]     : q_[2 * k + 1];
      r_[k] = keep + lane_xor<2>(send);
    }
    float u;
    {
      float keep = bb2 ? r_[1] : r_[0];
      float send = bb2 ? r_[0] : r_[1];
      u = keep + lane_xor<4>(send);
    }
    u += lane_xor<8>(u);                 // all lanes hold their 16-group sum for o=L&7
    if ((L & 8) == 0) sm.projp2[o8][w * 4 + (L >> 4)] = u;
    __syncthreads();                                  // ===== barrier 1
    {
      float4 pa = *reinterpret_cast<float4*>(&sm.projp2[o8][0]);
      float4 pb = *reinterpret_cast<float4*>(&sm.projp2[o8][4]);
      u = ((pa.x + pa.y) + (pa.z + pa.w)) + ((pb.x + pb.y) + (pb.z + pb.w));
    }
    if (t && tid == 0) {                              // emit out[t-1] (pipelined)
      float sy  = sm.outp[0][0] + sm.outp[1][0];
      float sy2 = sm.outp[0][1] + sm.outp[1][1];
      float sya = sm.outp[0][2] + sm.outp[1][2];
      float mn2 = sy * 0.0078125f;
      float vr2 = fmaf(sy2, 0.0078125f, -mn2 * mn2);
      float inv2 = fast_rsq(vr2 + 1e-5f);
      out[b * Tv + t - 1] = fmaf(inv2, sya - mn2 * SW, KB);
    }

    // ---- angles: tanh + LN(8) -> encode factors, broadcast via readlane
    float4 ipbv = *reinterpret_cast<float4*>(&sm.ipb[o8][0]);
    float tv = tanh_(u + ipbv.x);
    float m1 = tv, m2 = tv * tv;
    m1 += lane_xor<1>(m1); m2 += lane_xor<1>(m2);
    m1 += lane_xor<2>(m1); m2 += lane_xor<2>(m2);
    m1 += lane_xor<4>(m1); m2 += lane_xor<4>(m2);
    float pm = m1 * 0.125f;
    float pv = fmaf(m2, 0.125f, -pm * pm);
    float theta = (tv - pm) * fast_rsq(pv + 1e-5f) * ipbv.y + ipbv.z;
    float ph = theta * 0.5f;
    float cE = __cosf(ph), sE = __sinf(ph);
    float fm = cE - sE, fp = cE + sE;
    float f_[16];
    #pragma unroll
    for (int qq = 0; qq < 8; qq++) {
      f_[2 * qq]     = rdlane(fm, qq);
      f_[2 * qq + 1] = rdlane(fp, qq);
    }

    // ---- VQC encode (packed)
    v2 S[4];
    {
      float g01_[4];
      #pragma unroll
      for (int i = 0; i < 4; i++)
        g01_[i] = f_[(i >> 1) & 1] * f_[2 + (i & 1)];
      float lf = f_[6 + ((l5 >> 4) & 1)] * f_[8 + ((l5 >> 3) & 1)]
               * f_[10 + ((l5 >> 2) & 1)] * f_[12 + ((l5 >> 1) & 1)]
               * f_[14 + (l5 & 1)];
      lf *= 0.0625f;
      const v2 F45 = {f_[4], f_[5]};
      #pragma unroll
      for (int k = 0; k < 4; k++) {
        float tk = lf * g01_[k];
        v2 tk2 = {tk, tk};
        S[k] = tk2 * F45;
      }
    }

    // ---- 4 variational layers: fused [CNOT + RY(q3) + RY(q5)] one-DS-round burst,
    //      then VALU-only RYs (q0,q1,q2 reg/packed; q4,q6,q7 DPP)
    #pragma unroll
    for (int l = 0; l < 4; l++) {
      float c3 = csg[(l * 8 + 3) * 2], s3 = csg[(l * 8 + 3) * 2 + 1];
      float c5 = csg[(l * 8 + 5) * 2], s5 = csg[(l * 8 + 5) * 2 + 1];
      float t3 = (l5 & 16) ? s3 : -s3;
      float t5 = (l5 & 4)  ? s5 : -s5;
      float Ac = c3 * c5, Bc = t3 * c5, Cc = c3 * t5, Dc = t3 * t5;
      const v2 A2 = {Ac, Ac}, B2 = {Bc, Bc}, C2 = {Cc, Cc}, D2 = {Dc, Dc};
      float s00 = S[0].x, s01 = S[0].y, s10 = S[1].x, s11 = S[1].y,
            s20 = S[2].x, s21 = S[2].y, s30 = S[3].x, s31 = S[3].y;
      v2 N[4], N16[4], N4v[4], N20[4];
      // dest slot map (from verified R6 composed CNOT):
      //  S'0 <- (s00,p0 | s01,p1); S'1 <- (s11,p1 | s10,p0);
      //  S'2 <- (s30,p0 | s31,p1); S'3 <- (s21,p1 | s20,p0)
      N[0].x   = bperm(aP0[0], s00); N[0].y   = bperm(aP1[0], s01);
      N16[0].x = bperm(aP0[1], s00); N16[0].y = bperm(aP1[1], s01);
      N4v[0].x = bperm(aP0[2], s00); N4v[0].y = bperm(aP1[2], s01);
      N20[0].x = bperm(aP0[3], s00); N20[0].y = bperm(aP1[3], s01);
      N[1].x   = bperm(aP1[0], s11); N[1].y   = bperm(aP0[0], s10);
      N16[1].x = bperm(aP1[1], s11); N16[1].y = bperm(aP0[1], s10);
      N4v[1].x = bperm(aP1[2], s11); N4v[1].y = bperm(aP0[2], s10);
      N20[1].x = bperm(aP1[3], s11); N20[1].y = bperm(aP0[3], s10);
      N[2].x   = bperm(aP0[0], s30); N[2].y   = bperm(aP1[0], s31);
      N16[2].x = bperm(aP0[1], s30); N16[2].y = bperm(aP1[1], s31);
      N4v[2].x = bperm(aP0[2], s30); N4v[2].y = bperm(aP1[2], s31);
      N20[2].x = bperm(aP0[3], s30); N20[2].y = bperm(aP1[3], s31);
      N[3].x   = bperm(aP1[0], s21); N[3].y   = bperm(aP0[0], s20);
      N16[3].x = bperm(aP1[1], s21); N16[3].y = bperm(aP0[1], s20);
      N4v[3].x = bperm(aP1[2], s21); N4v[3].y = bperm(aP0[2], s20);
      N20[3].x = bperm(aP1[3], s21); N20[3].y = bperm(aP0[3], s20);
      #pragma unroll
      for (int k = 0; k < 4; k++)
        S[k] = pkfma(D2, N20[k], pkfma(C2, N4v[k], pkfma(B2, N16[k], A2 * N[k])));
      #define RYL(Q) { float2 cs2 = *reinterpret_cast<const float2*>(&csg[(l * 8 + Q) * 2]); \
                       ry_pk<Q>(S, cs2.x, cs2.y, l5); }
      RYL(0) RYL(1) RYL(2) RYL(4) RYL(6) RYL(7)
      #undef RYL
    }

    // ---- measure z_q (packed partials, scalar trees)
    v2 P[4];
    #pragma unroll
    for (int k = 0; k < 4; k++) P[k] = S[k] * S[k];
    v2 A = P[0] + P[2];          // {aa0, aa1}
    v2 B = P[1] + P[3];          // {aa2, aa3}
    v2 D = (P[0] - P[2]) + (P[1] - P[3]);
    float z0 = D.x + D.y;
    v2 Ev = A - B;
    float z1 = Ev.x + Ev.y;
    v2 G = A + B;
    float z2 = G.x - G.y;
    float S_ = G.x + G.y;
    z0 += lane_xor<1>(z0); z1 += lane_xor<1>(z1); z2 += lane_xor<1>(z2);
    z0 += lane_xor<2>(z0); z1 += lane_xor<2>(z1); z2 += lane_xor<2>(z2);
    z0 += lane_xor<4>(z0); z1 += lane_xor<4>(z1); z2 += lane_xor<4>(z2);
    z0 += lane_xor<8>(z0); z1 += lane_xor<8>(z1); z2 += lane_xor<8>(z2);
    z0 += lane_xor<16>(z0); z1 += lane_xor<16>(z1); z2 += lane_xor<16>(z2);
    float v, d, uS;
    v = lane_xor<16>(S_); d = S_ - v; uS = S_ + v;
    float z3 = (l5 & 16) ? -d : d;
    z3 += lane_xor<8>(z3); z3 += lane_xor<4>(z3); z3 += lane_xor<2>(z3); z3 += lane_xor<1>(z3);
    v = lane_xor<8>(uS); d = uS - v; uS = uS + v;
    float z4 = (l5 & 8) ? -d : d;
    z4 += lane_xor<4>(z4); z4 += lane_xor<2>(z4); z4 += lane_xor<1>(z4);
    v = lane_xor<4>(uS); d = uS - v; uS = uS + v;
    float z5 = (l5 & 4) ? -d : d;
    z5 += lane_xor<2>(z5); z5 += lane_xor<1>(z5);
    v = lane_xor<2>(uS); d = uS - v; uS = uS + v;
    float z6 = (l5 & 2) ? -d : d;
    z6 += lane_xor<1>(z6);
    v = lane_xor<1>(uS); d = uS - v;
    float z7 = (l5 & 1) ? -d : d;

    if (l5 < 8) {
      float zv = z0;
      zv = (l5 == 1) ? z1 : zv;
      zv = (l5 == 2) ? z2 : zv;
      zv = (l5 == 3) ? z3 : zv;
      zv = (l5 == 4) ? z4 : zv;
      zv = (l5 == 5) ? z5 : zv;
      zv = (l5 == 6) ? z6 : zv;
      zv = (l5 == 7) ? z7 : zv;
      sm.zbuf[gate * 8 + l5] = zv;
    }

    // ---- next-step emb partials (recurrence-independent; rides barrier 2)
    v2 acc = XN[0] * EW[0];
    acc = pkfma(XN[1], EW[1], acc);
    acc = pkfma(XN[2], EW[2], acc);
    acc = pkfma(XN[3], EW[3], acc);
    float en_raw = ebb + acc.x + acc.y;
    {
      float s1n = wave_sum(en_raw), s2n = wave_sum(en_raw * en_raw);
      if (L == 0) { sm.embp[w][0] = s1n; sm.embp[w][1] = s2n; }
    }
    __syncthreads();                                  // ===== barrier 2

    // ---- gate projections + LSTM cell (packed dot products)
    float acg[4];
    #pragma unroll
    for (int gg = 0; gg < 4; gg++) {
      float4 za0 = *reinterpret_cast<float4*>(&sm.zbuf[gg * 8]);
      float4 za1 = *reinterpret_cast<float4*>(&sm.zbuf[gg * 8 + 4]);
      v2 Z0 = {za0.x, za0.y}, Z1 = {za0.z, za0.w};
      v2 Z2 = {za1.x, za1.y}, Z3 = {za1.z, za1.w};
      v2 av = Z0 * GW[gg][0];
      av = pkfma(Z1, GW[gg][1], av);
      av = pkfma(Z2, GW[gg][2], av);
      av = pkfma(Z3, GW[gg][3], av);
      acg[gg] = gb[gg] + av.x + av.y;
    }
    float it = sigm_(acg[0]), ft = sigm_(acg[1]), gt = tanh_(acg[2]), ot = sigm_(acg[3]);
    c = ft * c + it * gt;
    h = ot * tanh_(c);

    // ---- normalize e_{t+1}
    float en;
    {
      float s1 = sm.embp[0][0] + sm.embp[1][0];
      float s2 = sm.embp[0][1] + sm.embp[1][1];
      float mn = s1 * 0.0078125f;
      float vr = fmaf(s2, 0.0078125f, -mn * mn);
      float inv = fast_rsq(vr + 1e-5f);
      en = (en_raw - mn) * inv * egg + ebt + pen;
    }

    // ---- epilogue partials for step t (consumed at next barrier 1)
    {
      float y = h + e;
      float ry0 = wave_sum(y), ry1 = wave_sum(y * y), ry2 = wave_sum(y * a_);
      if (L == 0) { sm.outp[w][0] = ry0; sm.outp[w][1] = ry1; sm.outp[w][2] = ry2; }
    }
    e = en;
  }

  __syncthreads();
  if (tid == 0) {
    float sy  = sm.outp[0][0] + sm.outp[1][0];
    float sy2 = sm.outp[0][1] + sm.outp[1][1];
    float sya = sm.outp[0][2] + sm.outp[1][2];
    float mn2 = sy * 0.0078125f;
    float vr2 = fmaf(sy2, 0.0078125f, -mn2 * mn2);
    float inv2 = fast_rsq(vr2 + 1e-5f);
    out[b * Tv + Tv - 1] = fmaf(inv2, sya - mn2 * SW, KB);
  }
}

extern "C" void kernel_launch(void* const* d_in, const int* in_sizes, int n_in,
                              void* d_out, int out_size, void* d_ws, size_t ws_size,
                              hipStream_t stream) {
  qlstm_kernel<<<dim3(1024), dim3(128), 0, stream>>>(
      (const float*)d_in[0],  (const float*)d_in[1],  (const float*)d_in[2],  (const float*)d_in[3],
      (const float*)d_in[4],  (const float*)d_in[5],  (const float*)d_in[6],  (const float*)d_in[7],
      (const float*)d_in[8],  (const float*)d_in[9],  (const float*)d_in[10], (const float*)d_in[11],
      (const float*)d_in[12], (const float*)d_in[13], (const float*)d_in[14], (const float*)d_in[15],
      (const float*)d_in[16], (const float*)d_in[17], (const float*)d_in[18], (const float*)d_in[19],
      (const float*)d_in[20], (const float*)d_in[21], (const float*)d_in[22], (const float*)d_in[23],
      (const float*)d_in[24], (const float*)d_in[25],
      (float*)d_out);
}

// Round 8
// 662.017 us; speedup vs baseline: 1.1374x; 1.1374x over previous
//
#include <hip/hip_runtime.h>

#define Tv 128

typedef float v2 __attribute__((ext_vector_type(2)));

__device__ __forceinline__ v2 pkfma(v2 a, v2 b, v2 c) {
  return __builtin_elementwise_fma(a, b, c);
}

// ---- DPP / cross-lane helpers
template<int CTRL>
__device__ __forceinline__ float dppx(float x) {
  return __int_as_float(__builtin_amdgcn_update_dpp(0, __float_as_int(x), CTRL, 0xF, 0xF, true));
}
__device__ __forceinline__ float dpp_rm(float x, int ctrl, int rm) {
  switch (ctrl) {
    default: return 0.f;
    case 0x111: return __int_as_float(__builtin_amdgcn_update_dpp(0, __float_as_int(x), 0x111, 0xF, 0xF, true));
    case 0x112: return __int_as_float(__builtin_amdgcn_update_dpp(0, __float_as_int(x), 0x112, 0xF, 0xF, true));
    case 0x114: return __int_as_float(__builtin_amdgcn_update_dpp(0, __float_as_int(x), 0x114, 0xF, 0xF, true));
    case 0x118: return __int_as_float(__builtin_amdgcn_update_dpp(0, __float_as_int(x), 0x118, 0xF, 0xF, true));
    case 0x142: return __int_as_float(__builtin_amdgcn_update_dpp(0, __float_as_int(x), 0x142, 0xA, 0xF, true));
    case 0x143: return __int_as_float(__builtin_amdgcn_update_dpp(0, __float_as_int(x), 0x143, 0xC, 0xF, true));
  }
}
// full-wave64 sum, broadcast via readlane(63)
__device__ __forceinline__ float wave_sum(float x) {
  x += dpp_rm(x, 0x111, 0xF);
  x += dpp_rm(x, 0x112, 0xF);
  x += dpp_rm(x, 0x114, 0xF);
  x += dpp_rm(x, 0x118, 0xF);
  x += dpp_rm(x, 0x142, 0xA);
  x += dpp_rm(x, 0x143, 0xC);
  return __int_as_float(__builtin_amdgcn_readlane(__float_as_int(x), 63));
}
template<int M>
__device__ __forceinline__ float lane_xor(float x) {
  if constexpr (M == 1)       return dppx<0xB1>(x);    // quad_perm [1,0,3,2]
  else if constexpr (M == 2)  return dppx<0x4E>(x);    // quad_perm [2,3,0,1]
  else if constexpr (M == 8)  return dppx<0x128>(x);   // row_ror:8 == xor8
  else if constexpr (M == 32) return __shfl_xor(x, 32, 64);
  else return __int_as_float(__builtin_amdgcn_ds_swizzle(__float_as_int(x), (M << 10) | 0x1F));
}
// xor4 substitute, VALID ONLY when x is already constant over lane bits 0,1:
// row_half_mirror (l -> l^7) == l^4 under that precondition. Pure DPP.
__device__ __forceinline__ float fold4(float x) { return dppx<0x141>(x); }
__device__ __forceinline__ float bperm(int addr, float x) {
  return __int_as_float(__builtin_amdgcn_ds_bpermute(addr, __float_as_int(x)));
}
__device__ __forceinline__ float rdlane(float x, int l) {
  return __int_as_float(__builtin_amdgcn_readlane(__float_as_int(x), l));
}
__device__ __forceinline__ float fast_rcp(float x){ return __builtin_amdgcn_rcpf(x); }
__device__ __forceinline__ float fast_rsq(float x){ return __builtin_amdgcn_rsqf(x); }
__device__ __forceinline__ float tanh_(float x){
  float e = __expf(2.0f * x);
  return 1.0f - 2.0f * fast_rcp(e + 1.0f);
}
__device__ __forceinline__ float sigm_(float x){
  return fast_rcp(1.0f + __expf(-x));
}

// State: 256 amps = 8 regs x 32 lanes, packed as v2 S[4]; s[r] = S[r>>1][r&1].
// idx = reg(3b: bits 7..5) | l5(5b: bits 4..0).
// q0 -> reg bit2; q1 -> reg bit1; q2 -> reg bit0 (x/y); q3..q7 -> lane masks 16,8,4,2,1.
// (q3,q5 handled by the fused swizzle burst in the layer loop)
template<int Q>
__device__ __forceinline__ void ry_pk(v2* S, float cc, float ss, int l5) {
  const v2 cc2 = {cc, cc};
  if constexpr (Q == 0) {
    const v2 ss2 = {ss, ss};
    #pragma unroll
    for (int k = 0; k < 2; k++) {
      v2 a0 = S[k], a1 = S[k + 2];
      S[k]     = pkfma(cc2, a0, -(ss2 * a1));
      S[k + 2] = pkfma(ss2, a0,  (cc2 * a1));
    }
  } else if constexpr (Q == 1) {
    const v2 ss2 = {ss, ss};
    #pragma unroll
    for (int k = 0; k < 4; k += 2) {
      v2 a0 = S[k], a1 = S[k + 1];
      S[k]     = pkfma(cc2, a0, -(ss2 * a1));
      S[k + 1] = pkfma(ss2, a0,  (cc2 * a1));
    }
  } else if constexpr (Q == 2) {
    const v2 nss = {-ss, ss};
    #pragma unroll
    for (int k = 0; k < 4; k++) {
      v2 a = S[k];
      v2 sw = __builtin_shufflevector(a, a, 1, 0);
      S[k] = pkfma(cc2, a, nss * sw);
    }
  } else {
    constexpr int m = 16 >> (Q - 3);
    float ssn = (l5 & m) ? ss : -ss;
    const v2 ssn2 = {ssn, ssn};
    #pragma unroll
    for (int k = 0; k < 4; k++) {
      v2 o;
      o.x = lane_xor<m>(S[k].x);
      o.y = lane_xor<m>(S[k].y);
      S[k] = pkfma(cc2, S[k], ssn2 * o);
    }
  }
}

struct __align__(16) SMem {
  float cs[4][66];     // per gate: (cos,sin) at [(l*8+q)*2]
  float ipb[8][4];     // (ip_b, in_g, in_b, 0)
  float zbuf[32];      // z[gate][qubit]
  float embp[2][2];    // emb-LN partials (s1,s2)
  float projp2[8][8];  // proj 16-group partials [o8][w*4+g]
  float outp[2][4];    // out-epilogue partials (init: SW/KB)
};

__global__ __launch_bounds__(128, 2) void qlstm_kernel(
    const float* __restrict__ x,     const float* __restrict__ pe,
    const float* __restrict__ emb_w, const float* __restrict__ emb_b,
    const float* __restrict__ emb_g, const float* __restrict__ emb_bt,
    const float* __restrict__ ip_w,  const float* __restrict__ ip_b,
    const float* __restrict__ in_g,  const float* __restrict__ in_b,
    const float* __restrict__ wq_i,  const float* __restrict__ wq_f,
    const float* __restrict__ wq_gt, const float* __restrict__ wq_o,
    const float* __restrict__ pi_w,  const float* __restrict__ pi_b,
    const float* __restrict__ pf_w,  const float* __restrict__ pf_b,
    const float* __restrict__ pg_w,  const float* __restrict__ pg_b,
    const float* __restrict__ po_w,  const float* __restrict__ po_b,
    const float* __restrict__ on_g,  const float* __restrict__ on_b,
    const float* __restrict__ out_w, const float* __restrict__ out_b,
    float* __restrict__ out)
{
  __shared__ SMem sm;
  const int tid = threadIdx.x;          // 0..127 = row j
  const int b   = blockIdx.x;
  const int w   = tid >> 6;             // wave 0/1
  const int L   = tid & 63;
  const int l5  = L & 31;
  const int gate = w * 2 + (L >> 5);    // 0..3 = i,f,g,o
  const int o8  = L & 7;

  // ---- stage (cos,sin) table
  {
    int gg = tid >> 5, rem = tid & 31;
    const float* wsel = (gg == 0) ? wq_i : (gg == 1) ? wq_f : (gg == 2) ? wq_gt : wq_o;
    float th = wsel[rem] * 0.5f;
    sm.cs[gg][rem * 2]     = __cosf(th);
    sm.cs[gg][rem * 2 + 1] = __sinf(th);
  }
  if (tid < 8) {
    sm.ipb[tid][0] = ip_b[tid];
    sm.ipb[tid][1] = in_g[tid];
    sm.ipb[tid][2] = in_b[tid];
    sm.ipb[tid][3] = 0.0f;
  }

  // ---- persistent per-thread weights (row j = tid)
  const int j = tid;
  v2 EW[4];
  {
    float4 a = *reinterpret_cast<const float4*>(emb_w + j * 8);
    float4 c = *reinterpret_cast<const float4*>(emb_w + j * 8 + 4);
    EW[0] = {a.x, a.y}; EW[1] = {a.z, a.w}; EW[2] = {c.x, c.y}; EW[3] = {c.z, c.w};
  }
  float ebb = emb_b[j], egg = emb_g[j], ebt = emb_bt[j];
  v2 IPW1[4], IPW2[4];
  #pragma unroll
  for (int k = 0; k < 4; k++) {
    IPW1[k] = {ip_w[(2 * k) * 256 + j],       ip_w[(2 * k + 1) * 256 + j]};
    IPW2[k] = {ip_w[(2 * k) * 256 + 128 + j], ip_w[(2 * k + 1) * 256 + 128 + j]};
  }
  v2 GW[4][4];
  #pragma unroll
  for (int gg = 0; gg < 4; gg++) {
    const float* pw = (gg == 0) ? pi_w : (gg == 1) ? pf_w : (gg == 2) ? pg_w : po_w;
    float4 a = *reinterpret_cast<const float4*>(pw + j * 8);
    float4 c = *reinterpret_cast<const float4*>(pw + j * 8 + 4);
    GW[gg][0] = {a.x, a.y}; GW[gg][1] = {a.z, a.w};
    GW[gg][2] = {c.x, c.y}; GW[gg][3] = {c.z, c.w};
  }
  float gb[4] = {pi_b[j], pf_b[j], pg_b[j], po_b[j]};
  float ong = on_g[j], onb = on_b[j], ow_ = out_w[j];
  float outb = out_b[0];
  float a_ = ong * ow_;

  // Composed per-layer CNOT permutation (verified R4/R6)
  const int grp = L & 32;
  int aC0, aC1;
  {
    int l1 = l5 ^ ((l5 & 16) >> 1) ^ ((l5 & 4) >> 1);
    int lb = l1 ^ ((l1 & 8) >> 1) ^ ((l1 & 2) >> 1);
    aC0 = (grp | lb) << 2;
    aC1 = (grp | (lb ^ 16)) << 2;
  }

  const float* csg = sm.cs[gate];
  float h = 0.f, c = 0.f;
  const float* xbase = x + (size_t)b * Tv * 8;

  // ---- pre-loop: e_0 + SW/KB partials, single barrier
  float e;
  {
    float4 a = *reinterpret_cast<const float4*>(xbase);
    float4 cq = *reinterpret_cast<const float4*>(xbase + 4);
    v2 XT[4] = {{a.x,a.y},{a.z,a.w},{cq.x,cq.y},{cq.z,cq.w}};
    v2 acc = XT[0] * EW[0];
    acc = pkfma(XT[1], EW[1], acc);
    acc = pkfma(XT[2], EW[2], acc);
    acc = pkfma(XT[3], EW[3], acc);
    float er = ebb + acc.x + acc.y;
    float s1 = wave_sum(er), s2 = wave_sum(er * er);
    float r0 = wave_sum(a_), r1 = wave_sum(onb * ow_);
    if (L == 0) {
      sm.embp[w][0] = s1; sm.embp[w][1] = s2;
      sm.outp[w][0] = r0; sm.outp[w][1] = r1;
    }
    __syncthreads();
    s1 = sm.embp[0][0] + sm.embp[1][0];
    s2 = sm.embp[0][1] + sm.embp[1][1];
    float mn = s1 * 0.0078125f;
    float vr = fmaf(s2, 0.0078125f, -mn * mn);
    float inv = fast_rsq(vr + 1e-5f);
    e = (er - mn) * inv * egg + ebt + pe[j];
  }
  const float SW = sm.outp[0][0] + sm.outp[1][0];
  const float KB = sm.outp[0][1] + sm.outp[1][1] + outb;

  #pragma unroll 1
  for (int t = 0; t < Tv; t++) {
    // ---- prefetch next x,pe
    v2 XN[4]; float pen;
    {
      int tn = (t + 1) & (Tv - 1);
      float4 a = *reinterpret_cast<const float4*>(xbase + tn * 8);
      float4 cq = *reinterpret_cast<const float4*>(xbase + tn * 8 + 4);
      XN[0] = {a.x,a.y}; XN[1] = {a.z,a.w}; XN[2] = {cq.x,cq.y}; XN[3] = {cq.z,cq.w};
      pen = pe[tn * 128 + j];
    }

    // ---- proj: p_o = e*ipw1[o] + h*ipw2[o] (packed); butterfly to m8, LDS partials
    const v2 e2 = {e, e}, h2 = {h, h};
    v2 P2[4];
    #pragma unroll
    for (int k = 0; k < 4; k++)
      P2[k] = pkfma(e2, IPW1[k], h2 * IPW2[k]);
    const int bb0 = L & 1, bb1 = L & 2, bb2 = L & 4;
    float q_[4];
    #pragma unroll
    for (int k = 0; k < 4; k++) {
      float keep = bb0 ? P2[k].y : P2[k].x;
      float send = bb0 ? P2[k].x : P2[k].y;
      q_[k] = keep + lane_xor<1>(send);
    }
    float r_[2];
    #pragma unroll
    for (int k = 0; k < 2; k++) {
      float keep = bb1 ? q_[2 * k + 1] : q_[2 * k];
      float send = bb1 ? q_[2 * k]     : q_[2 * k + 1];
      r_[k] = keep + lane_xor<2>(send);
    }
    float u;
    {
      float keep = bb2 ? r_[1] : r_[0];
      float send = bb2 ? r_[0] : r_[1];
      u = keep + lane_xor<4>(send);    // true butterfly: must be real xor4 (DS)
    }
    u += lane_xor<8>(u);               // 16-group sum for o = L&7
    if ((L & 8) == 0) sm.projp2[o8][w * 4 + (L >> 4)] = u;
    __syncthreads();                                  // ===== barrier 1
    {
      float4 pa = *reinterpret_cast<float4*>(&sm.projp2[o8][0]);
      float4 pb = *reinterpret_cast<float4*>(&sm.projp2[o8][4]);
      u = ((pa.x + pa.y) + (pa.z + pa.w)) + ((pb.x + pb.y) + (pb.z + pb.w));
    }
    if (t && tid == 0) {                              // emit out[t-1] (pipelined)
      float sy  = sm.outp[0][0] + sm.outp[1][0];
      float sy2 = sm.outp[0][1] + sm.outp[1][1];
      float sya = sm.outp[0][2] + sm.outp[1][2];
      float mn2 = sy * 0.0078125f;
      float vr2 = fmaf(sy2, 0.0078125f, -mn2 * mn2);
      float inv2 = fast_rsq(vr2 + 1e-5f);
      out[b * Tv + t - 1] = fmaf(inv2, sya - mn2 * SW, KB);
    }

    // ---- angles: tanh + LN(8) (all-DPP: m1, m2, then xor7==xor4) -> factors
    float4 ipbv = *reinterpret_cast<float4*>(&sm.ipb[o8][0]);
    float tv = tanh_(u + ipbv.x);
    float m1 = tv, m2 = tv * tv;
    m1 += lane_xor<1>(m1); m2 += lane_xor<1>(m2);
    m1 += lane_xor<2>(m1); m2 += lane_xor<2>(m2);
    m1 += fold4(m1);       m2 += fold4(m2);
    float pm = m1 * 0.125f;
    float pv = fmaf(m2, 0.125f, -pm * pm);
    float theta = (tv - pm) * fast_rsq(pv + 1e-5f) * ipbv.y + ipbv.z;
    float ph = theta * 0.5f;
    float cE = __cosf(ph), sE = __sinf(ph);
    float fm = cE - sE, fp = cE + sE;
    float f_[16];
    #pragma unroll
    for (int qq = 0; qq < 8; qq++) {
      f_[2 * qq]     = rdlane(fm, qq);
      f_[2 * qq + 1] = rdlane(fp, qq);
    }

    // ---- VQC encode (packed)
    v2 S[4];
    {
      float g01_[4];
      #pragma unroll
      for (int i = 0; i < 4; i++)
        g01_[i] = f_[(i >> 1) & 1] * f_[2 + (i & 1)];
      float lf = f_[6 + ((l5 >> 4) & 1)] * f_[8 + ((l5 >> 3) & 1)]
               * f_[10 + ((l5 >> 2) & 1)] * f_[12 + ((l5 >> 1) & 1)]
               * f_[14 + (l5 & 1)];
      lf *= 0.0625f;
      const v2 F45 = {f_[4], f_[5]};
      #pragma unroll
      for (int k = 0; k < 4; k++) {
        float tk = lf * g01_[k];
        v2 tk2 = {tk, tk};
        S[k] = tk2 * F45;
      }
    }

    // ---- 4 variational layers: composed bpermute (8 ops) + fused RY(q3,q5)
    //      swizzle burst (masks 16,4,20 — one DS segment) + VALU/DPP RYs
    #pragma unroll
    for (int l = 0; l < 4; l++) {
      v2 N0, N1, N2, N3;
      N0.x = bperm(aC0, S[0].x); N0.y = bperm(aC1, S[0].y);
      N1.x = bperm(aC1, S[1].y); N1.y = bperm(aC0, S[1].x);
      N2.x = bperm(aC0, S[3].x); N2.y = bperm(aC1, S[3].y);
      N3.x = bperm(aC1, S[2].y); N3.y = bperm(aC0, S[2].x);
      S[0] = N0; S[1] = N1; S[2] = N2; S[3] = N3;
      // fused RY(q3)+RY(q5): new = c3c5*s + t3c5*s^16 + c3t5*s^4 + t3t5*s^20
      {
        float c3 = csg[(l * 8 + 3) * 2], s3v = csg[(l * 8 + 3) * 2 + 1];
        float c5 = csg[(l * 8 + 5) * 2], s5v = csg[(l * 8 + 5) * 2 + 1];
        float t3 = (l5 & 16) ? s3v : -s3v;
        float t5 = (l5 & 4)  ? s5v : -s5v;
        float Ac = c3 * c5, Bc = t3 * c5, Cc = c3 * t5, Dc = t3 * t5;
        const v2 A2 = {Ac, Ac}, B2 = {Bc, Bc}, C2 = {Cc, Cc}, D2 = {Dc, Dc};
        v2 N16[4], N4[4], N20[4];
        #pragma unroll
        for (int k = 0; k < 4; k++) {
          N16[k].x = lane_xor<16>(S[k].x); N16[k].y = lane_xor<16>(S[k].y);
          N4[k].x  = lane_xor<4>(S[k].x);  N4[k].y  = lane_xor<4>(S[k].y);
          N20[k].x = lane_xor<20>(S[k].x); N20[k].y = lane_xor<20>(S[k].y);
        }
        #pragma unroll
        for (int k = 0; k < 4; k++)
          S[k] = pkfma(D2, N20[k], pkfma(C2, N4[k], pkfma(B2, N16[k], A2 * S[k])));
      }
      #define RYL(Q) { float2 cs2 = *reinterpret_cast<const float2*>(&csg[(l * 8 + Q) * 2]); \
                       ry_pk<Q>(S, cs2.x, cs2.y, l5); }
      RYL(0) RYL(1) RYL(2) RYL(4) RYL(6) RYL(7)
      #undef RYL
    }

    // ---- measure z_q: DPP trunk + peels; ONE final m16 swizzle burst
    v2 P[4];
    #pragma unroll
    for (int k = 0; k < 4; k++) P[k] = S[k] * S[k];
    v2 A = P[0] + P[2];
    v2 B = P[1] + P[3];
    v2 D = (P[0] - P[2]) + (P[1] - P[3]);
    float z0 = D.x + D.y;
    v2 Ev = A - B;
    float z1 = Ev.x + Ev.y;
    v2 G = A + B;
    float z2 = G.x - G.y;
    float S_ = G.x + G.y;
    // z0..z2: plain folds, all DPP until m16
    z0 += lane_xor<1>(z0); z1 += lane_xor<1>(z1); z2 += lane_xor<1>(z2);
    z0 += lane_xor<2>(z0); z1 += lane_xor<2>(z1); z2 += lane_xor<2>(z2);
    z0 += fold4(z0);       z1 += fold4(z1);       z2 += fold4(z2);
    z0 += lane_xor<8>(z0); z1 += lane_xor<8>(z1); z2 += lane_xor<8>(z2);
    // trunk with peels (signs at peel, then DPP folds)
    float v1 = lane_xor<1>(S_);
    float S1 = S_ + v1;
    float d1 = S_ - v1;
    float z7 = (l5 & 1) ? -d1 : d1;
    z7 += lane_xor<2>(z7); z7 += fold4(z7); z7 += lane_xor<8>(z7);
    float v2s = lane_xor<2>(S1);
    float S12 = S1 + v2s;
    float d2 = S1 - v2s;
    float z6 = (l5 & 2) ? -d2 : d2;
    z6 += fold4(z6); z6 += lane_xor<8>(z6);
    float v4 = fold4(S12);           // S12 const over bits 0,1 -> xor7==xor4
    float S124 = S12 + v4;
    float d4 = S12 - v4;
    float z5 = (l5 & 4) ? -d4 : d4;
    z5 += lane_xor<8>(z5);
    float v8 = lane_xor<8>(S124);
    float S1248 = S124 + v8;
    float d8 = S124 - v8;
    float z4 = (l5 & 8) ? -d8 : d8;
    // final cross-row folds: one parallel DS burst (8 independent swizzles)
    z0 += lane_xor<16>(z0);
    z1 += lane_xor<16>(z1);
    z2 += lane_xor<16>(z2);
    z4 += lane_xor<16>(z4);
    z5 += lane_xor<16>(z5);
    z6 += lane_xor<16>(z6);
    z7 += lane_xor<16>(z7);
    float v16 = lane_xor<16>(S1248);
    float d16 = S1248 - v16;
    float z3 = (l5 & 16) ? -d16 : d16;

    if (l5 < 8) {
      float zv = z0;
      zv = (l5 == 1) ? z1 : zv;
      zv = (l5 == 2) ? z2 : zv;
      zv = (l5 == 3) ? z3 : zv;
      zv = (l5 == 4) ? z4 : zv;
      zv = (l5 == 5) ? z5 : zv;
      zv = (l5 == 6) ? z6 : zv;
      zv = (l5 == 7) ? z7 : zv;
      sm.zbuf[gate * 8 + l5] = zv;
    }

    // ---- next-step emb partials (recurrence-independent; rides barrier 2)
    v2 acc = XN[0] * EW[0];
    acc = pkfma(XN[1], EW[1], acc);
    acc = pkfma(XN[2], EW[2], acc);
    acc = pkfma(XN[3], EW[3], acc);
    float en_raw = ebb + acc.x + acc.y;
    {
      float s1n = wave_sum(en_raw), s2n = wave_sum(en_raw * en_raw);
      if (L == 0) { sm.embp[w][0] = s1n; sm.embp[w][1] = s2n; }
    }
    __syncthreads();                                  // ===== barrier 2

    // ---- gate projections + LSTM cell (packed dot products)
    float acg[4];
    #pragma unroll
    for (int gg = 0; gg < 4; gg++) {
      float4 za0 = *reinterpret_cast<float4*>(&sm.zbuf[gg * 8]);
      float4 za1 = *reinterpret_cast<float4*>(&sm.zbuf[gg * 8 + 4]);
      v2 Z0 = {za0.x, za0.y}, Z1 = {za0.z, za0.w};
      v2 Z2 = {za1.x, za1.y}, Z3 = {za1.z, za1.w};
      v2 av = Z0 * GW[gg][0];
      av = pkfma(Z1, GW[gg][1], av);
      av = pkfma(Z2, GW[gg][2], av);
      av = pkfma(Z3, GW[gg][3], av);
      acg[gg] = gb[gg] + av.x + av.y;
    }
    float it = sigm_(acg[0]), ft = sigm_(acg[1]), gt = tanh_(acg[2]), ot = sigm_(acg[3]);
    c = ft * c + it * gt;
    h = ot * tanh_(c);

    // ---- normalize e_{t+1}
    float en;
    {
      float s1 = sm.embp[0][0] + sm.embp[1][0];
      float s2 = sm.embp[0][1] + sm.embp[1][1];
      float mn = s1 * 0.0078125f;
      float vr = fmaf(s2, 0.0078125f, -mn * mn);
      float inv = fast_rsq(vr + 1e-5f);
      en = (en_raw - mn) * inv * egg + ebt + pen;
    }

    // ---- epilogue partials for step t (consumed at next barrier 1)
    {
      float y = h + e;
      float ry0 = wave_sum(y), ry1 = wave_sum(y * y), ry2 = wave_sum(y * a_);
      if (L == 0) { sm.outp[w][0] = ry0; sm.outp[w][1] = ry1; sm.outp[w][2] = ry2; }
    }
    e = en;
  }

  __syncthreads();
  if (tid == 0) {
    float sy  = sm.outp[0][0] + sm.outp[1][0];
    float sy2 = sm.outp[0][1] + sm.outp[1][1];
    float sya = sm.outp[0][2] + sm.outp[1][2];
    float mn2 = sy * 0.0078125f;
    float vr2 = fmaf(sy2, 0.0078125f, -mn2 * mn2);
    float inv2 = fast_rsq(vr2 + 1e-5f);
    out[b * Tv + Tv - 1] = fmaf(inv2, sya - mn2 * SW, KB);
  }
}

extern "C" void kernel_launch(void* const* d_in, const int* in_sizes, int n_in,
                              void* d_out, int out_size, void* d_ws, size_t ws_size,
                              hipStream_t stream) {
  qlstm_kernel<<<dim3(1024), dim3(128), 0, stream>>>(
      (const float*)d_in[0],  (const float*)d_in[1],  (const float*)d_in[2],  (const float*)d_in[3],
      (const float*)d_in[4],  (const float*)d_in[5],  (const float*)d_in[6],  (const float*)d_in[7],
      (const float*)d_in[8],  (const float*)d_in[9],  (const float*)d_in[10], (const float*)d_in[11],
      (const float*)d_in[12], (const float*)d_in[13], (const float*)d_in[14], (const float*)d_in[15],
      (const float*)d_in[16], (const float*)d_in[17], (const float*)d_in[18], (const float*)d_in[19],
      (const float*)d_in[20], (const float*)d_in[21], (const float*)d_in[22], (const float*)d_in[23],
      (const float*)d_in[24], (const float*)d_in[25],
      (float*)d_out);
}